// Round 3
// baseline (332.440 us; speedup 1.0000x reference)
//
#include <hip/hip_runtime.h>
#include <stdint.h>
#include <stddef.h>

#define DEVINL __device__ __forceinline__

typedef unsigned short u16;
typedef unsigned int u32;
typedef __attribute__((ext_vector_type(8))) short short8;
typedef __attribute__((ext_vector_type(4))) float f32x4;
typedef __attribute__((ext_vector_type(4))) u32 u32x4;
typedef __attribute__((ext_vector_type(2))) u32 u32x2;

// log2(e)/8 : folded into W_q / b_q so flash's exp2 needs no multiply
#define QSCALE 0.18033688011112042f

// ---------- helpers ----------
DEVINL u16 f2bf(float f) {
    u32 u = __builtin_bit_cast(u32, f);
    u32 r = (u + 0x7fffu + ((u >> 16) & 1u)) >> 16;   // RNE
    return (u16)r;
}

DEVINL void gld_lds16(const void* g, void* l) {
    __builtin_amdgcn_global_load_lds(
        (__attribute__((address_space(1))) u32*)(uintptr_t)g,
        (__attribute__((address_space(3))) u32*)l, 16, 0, 0);
}

// pack two fp32 -> bf16x2 by truncation (bias cancels: denominator sums the same bf16 P)
DEVINL u32 pack_bf16_trunc(float lo, float hi) {
    return __builtin_amdgcn_perm(__builtin_bit_cast(u32, hi),
                                 __builtin_bit_cast(u32, lo), 0x07060302u);
}

// ---------- fused input prep: casts + scale folding, one launch ----------
// blocks [0,4096): x -> xb ; [4096,5632): w_qkv -> wqb (Q rows scaled)
// [5632,6144): w_o -> wob ; [6144,6156): b_qkv scale -> bsc
__global__ void prep_inputs(const float* __restrict__ x, const float* __restrict__ wqkv,
                            const float* __restrict__ bqkv, const float* __restrict__ wo,
                            u16* __restrict__ xb, u16* __restrict__ wqb,
                            u16* __restrict__ wob, float* __restrict__ bsc) {
    int blk = blockIdx.x;
    if (blk < 6144) {
        const float* src; u16* dst; int base; bool qscale = false;
        if (blk < 4096)      { src = x;    dst = xb;  base = blk; }
        else if (blk < 5632) { src = wqkv; dst = wqb; base = blk - 4096; qscale = true; }
        else                 { src = wo;   dst = wob; base = blk - 5632; }
        int i = (base * 256 + threadIdx.x) * 8;
        float sc = 1.0f;
        if (qscale) { int row = i >> 10; if ((row % 192) < 64) sc = QSCALE; }
        float4 a = *(const float4*)(src + i);
        float4 c = *(const float4*)(src + i + 4);
        union { u16 s[8]; u32x4 v; } t;
        t.s[0] = f2bf(a.x * sc); t.s[1] = f2bf(a.y * sc); t.s[2] = f2bf(a.z * sc); t.s[3] = f2bf(a.w * sc);
        t.s[4] = f2bf(c.x * sc); t.s[5] = f2bf(c.y * sc); t.s[6] = f2bf(c.z * sc); t.s[7] = f2bf(c.w * sc);
        *(u32x4*)(dst + i) = t.v;
    } else {
        int i = (blk - 6144) * 256 + threadIdx.x;   // 0..3071
        float sc = ((i % 192) < 64) ? QSCALE : 1.0f;
        bsc[i] = bqkv[i] * sc;
    }
}

// ---------- GEMM  C[M,N] = A[M,K] * B[N,K]^T + bias[N] ----------
template <int OUT_BF16>
__global__ void gemm_abt(const u16* __restrict__ A, const u16* __restrict__ Bm,
                         const float* __restrict__ bias, void* __restrict__ Cout,
                         int M, int N, int K) {
    __shared__ u16 As[128 * 32];
    __shared__ u16 Bs[128 * 32];
    const int tid = threadIdx.x;
    const int lane = tid & 63;
    const int wv = tid >> 6, wr = wv >> 1, wc = wv & 1;
    const int l15 = lane & 15, quad = lane >> 4;
    const int m0 = blockIdx.y * 128, n0 = blockIdx.x * 128;

    f32x4 acc[4][4];
#pragma unroll
    for (int i = 0; i < 4; i++)
#pragma unroll
        for (int j = 0; j < 4; j++) acc[i][j] = (f32x4){0.f, 0.f, 0.f, 0.f};

    const u16* Ab = A + (size_t)m0 * K;
    const u16* Bb = Bm + (size_t)n0 * K;
    const int srow = tid >> 2;
    const int sc8 = (tid & 3) * 8;

    for (int k0 = 0; k0 < K; k0 += 32) {
#pragma unroll
        for (int i = 0; i < 2; i++) {
            int row = i * 64 + srow;
            gld_lds16(Ab + (size_t)row * K + k0 + sc8, (char*)As + (size_t)(i * 256 + tid) * 16);
            gld_lds16(Bb + (size_t)row * K + k0 + sc8, (char*)Bs + (size_t)(i * 256 + tid) * 16);
        }
        __syncthreads();
        short8 af[4], bf8[4];
#pragma unroll
        for (int mi = 0; mi < 4; mi++)
            af[mi] = *(const short8*)(As + (wr * 64 + mi * 16 + l15) * 32 + quad * 8);
#pragma unroll
        for (int ni = 0; ni < 4; ni++)
            bf8[ni] = *(const short8*)(Bs + (wc * 64 + ni * 16 + l15) * 32 + quad * 8);
#pragma unroll
        for (int mi = 0; mi < 4; mi++)
#pragma unroll
            for (int ni = 0; ni < 4; ni++)
                acc[mi][ni] = __builtin_amdgcn_mfma_f32_16x16x32_bf16(af[mi], bf8[ni], acc[mi][ni], 0, 0, 0);
        __syncthreads();
    }

#pragma unroll
    for (int mi = 0; mi < 4; mi++) {
        int row_b = m0 + wr * 64 + mi * 16 + quad * 4;
#pragma unroll
        for (int ni = 0; ni < 4; ni++) {
            int col = n0 + wc * 64 + ni * 16 + l15;
            float bv = bias[col];
#pragma unroll
            for (int r = 0; r < 4; r++) {
                float v = acc[mi][ni][r] + bv;
                size_t idx = (size_t)(row_b + r) * N + col;
                if (OUT_BF16) ((u16*)Cout)[idx] = f2bf(v);
                else          ((float*)Cout)[idx] = v;
            }
        }
    }
}

// ---------- transpose V slice of qkv into vt[bh][d][s] ----------
__global__ void transpose_v(const u16* __restrict__ qkv, u16* __restrict__ vtb) {
    __shared__ u16 Vl[64][72];
    const int tid = threadIdx.x;
    const int s0 = blockIdx.x * 64;
    const int bh = blockIdx.y, b = bh >> 4, h = bh & 15;
    const u16* src = qkv + (size_t)(b * 2048 + s0) * 3072 + h * 192 + 128;
#pragma unroll
    for (int i = 0; i < 2; i++) {
        int cid = i * 256 + tid;
        int rs = cid >> 3, c8 = (cid & 7) * 8;
        *(u32x4*)(&Vl[rs][c8]) = *(const u32x4*)(src + (size_t)rs * 3072 + c8);
    }
    __syncthreads();
#pragma unroll
    for (int i = 0; i < 2; i++) {
        int cid = i * 256 + tid;
        int d = cid >> 3, sc = cid & 7;
        union { u16 s[8]; u32x4 v; } t;
#pragma unroll
        for (int j = 0; j < 8; j++) t.s[j] = Vl[sc * 8 + j][d];
        *(u32x4*)(vtb + ((size_t)bh * 64 + d) * 2048 + s0 + sc * 8) = t.v;
    }
}

// ---------- flash attention v3 ----------
// K staged 128 keys via global_load_lds (XOR-swizzled source, lane-linear dest),
// V B-frags direct from global vt, P per-wave LDS round-trip, no online max,
// denominator via ones-MFMA. LDS 34 KB.
__launch_bounds__(256, 4)
__global__ void flash_attn(const u16* __restrict__ qkv, const u16* __restrict__ vt,
                           u16* __restrict__ vals2) {
    __shared__ u16 Ks[128 * 64];     // 16 KB, 16B chunks XOR-swizzled within rows
    __shared__ u16 Ps[4][32 * 72];   // 18 KB, per-wave P tiles

    const int tid = threadIdx.x;
    const int lane = tid & 63, wv = tid >> 6;
    const int l15 = lane & 15, quad = lane >> 4;
    const int s0 = blockIdx.x * 128;
    const int bh = blockIdx.y, b = bh >> 4, h = bh & 15;

    // Q fragments in registers (q rows pre-scaled by log2e/8 at cast time)
    short8 qf[2][2];
    const u16* qbase = qkv + (size_t)(b * 2048 + s0 + wv * 32) * 3072 + h * 192;
#pragma unroll
    for (int qi = 0; qi < 2; qi++)
#pragma unroll
        for (int ks = 0; ks < 2; ks++)
            qf[qi][ks] = *(const short8*)(qbase + (size_t)(qi * 16 + l15) * 3072 + ks * 32 + quad * 8);

    f32x4 o_acc[2][4];
    f32x4 sum_acc[2];
#pragma unroll
    for (int qi = 0; qi < 2; qi++) {
        sum_acc[qi] = (f32x4){0.f, 0.f, 0.f, 0.f};
#pragma unroll
        for (int nd = 0; nd < 4; nd++) o_acc[qi][nd] = (f32x4){0.f, 0.f, 0.f, 0.f};
    }

    const u16* kg = qkv + (size_t)(b * 2048) * 3072 + h * 192 + 64;
    const u16* vg = vt + (size_t)bh * 64 * 2048;

    // K staging maps (hoisted): linear LDS chunk t = i*256+tid; row = t>>3,
    // global chunk c = (t&7) ^ (row&7). Frag read undoes the XOR with l15&7.
    int srcoff[4]; int dstoff[4];
#pragma unroll
    for (int i = 0; i < 4; i++) {
        int t = i * 256 + tid;
        int row = t >> 3;
        int c = (t & 7) ^ (row & 7);
        srcoff[i] = row * 3072 + c * 8;          // u16 units
        dstoff[i] = (i * 256 + wv * 64) * 16;    // bytes, wave-uniform base
    }

    const short8 ones = (short8){0x3F80, 0x3F80, 0x3F80, 0x3F80, 0x3F80, 0x3F80, 0x3F80, 0x3F80};

    for (int kb = 0; kb < 2048; kb += 128) {
        __syncthreads();
#pragma unroll
        for (int i = 0; i < 4; i++)
            gld_lds16(kg + (size_t)kb * 3072 + srcoff[i], (char*)Ks + dstoff[i]);
        __syncthreads();

#pragma unroll
        for (int sub = 0; sub < 2; sub++) {
            // S^T = K * Q^T : key = ki*16+quad*4+r, q = qi*16+l15
            f32x4 s_acc[4][2];
#pragma unroll
            for (int ki = 0; ki < 4; ki++)
#pragma unroll
                for (int qi = 0; qi < 2; qi++) s_acc[ki][qi] = (f32x4){0.f, 0.f, 0.f, 0.f};
#pragma unroll
            for (int ki = 0; ki < 4; ki++) {
#pragma unroll
                for (int ks = 0; ks < 2; ks++) {
                    short8 kf = *(const short8*)(Ks + (sub * 64 + ki * 16 + l15) * 64 +
                                                 (((ks * 4 + quad) ^ (l15 & 7)) * 8));
#pragma unroll
                    for (int qi = 0; qi < 2; qi++)
                        s_acc[ki][qi] = __builtin_amdgcn_mfma_f32_16x16x32_bf16(kf, qf[qi][ks], s_acc[ki][qi], 0, 0, 0);
                }
            }

            // P = exp2(S^T) -> truncate-pack bf16 -> per-wave LDS (A-layout [q][key])
#pragma unroll
            for (int ki = 0; ki < 4; ki++)
#pragma unroll
                for (int qi = 0; qi < 2; qi++) {
                    float p0 = __builtin_amdgcn_exp2f(s_acc[ki][qi][0]);
                    float p1 = __builtin_amdgcn_exp2f(s_acc[ki][qi][1]);
                    float p2 = __builtin_amdgcn_exp2f(s_acc[ki][qi][2]);
                    float p3 = __builtin_amdgcn_exp2f(s_acc[ki][qi][3]);
                    u32x2 pk = (u32x2){pack_bf16_trunc(p0, p1), pack_bf16_trunc(p2, p3)};
                    *(u32x2*)(Ps[wv] + (qi * 16 + l15) * 72 + ki * 16 + quad * 4) = pk;
                }

            // PV over 2 chunks of 32 keys; V frags straight from global (vt rows)
#pragma unroll
            for (int c = 0; c < 2; c++) {
                short8 vf[4];
#pragma unroll
                for (int nd = 0; nd < 4; nd++)
                    vf[nd] = *(const short8*)(vg + (size_t)(nd * 16 + l15) * 2048 +
                                              kb + sub * 64 + c * 32 + quad * 8);
                short8 ap[2];
#pragma unroll
                for (int qi = 0; qi < 2; qi++)
                    ap[qi] = *(const short8*)(Ps[wv] + (qi * 16 + l15) * 72 + c * 32 + quad * 8);
#pragma unroll
                for (int qi = 0; qi < 2; qi++)
                    sum_acc[qi] = __builtin_amdgcn_mfma_f32_16x16x32_bf16(ap[qi], ones, sum_acc[qi], 0, 0, 0);
#pragma unroll
                for (int nd = 0; nd < 4; nd++)
#pragma unroll
                    for (int qi = 0; qi < 2; qi++)
                        o_acc[qi][nd] = __builtin_amdgcn_mfma_f32_16x16x32_bf16(ap[qi], vf[nd], o_acc[qi][nd], 0, 0, 0);
            }
        }
    }

    // epilogue: normalize (sum broadcast across l15 by ones-MFMA), write vals2
    // in the no-head-transpose reshape layout.
#pragma unroll
    for (int qi = 0; qi < 2; qi++) {
        f32x4 inv;
#pragma unroll
        for (int r = 0; r < 4; r++) inv[r] = 1.0f / sum_acc[qi][r];
#pragma unroll
        for (int nd = 0; nd < 4; nd++) {
            int d = nd * 16 + l15;
#pragma unroll
            for (int r = 0; r < 4; r++) {
                int s = s0 + wv * 32 + qi * 16 + quad * 4 + r;
                size_t row2 = (size_t)(b * 2048 + h * 128 + (s >> 4));
                int col2 = ((s & 15) << 6) + d;
                vals2[row2 * 1024 + col2] = f2bf(o_acc[qi][nd][r] * inv[r]);
            }
        }
    }
}

// ---------- launch ----------
extern "C" void kernel_launch(void* const* d_in, const int* in_sizes, int n_in,
                              void* d_out, int out_size, void* d_ws, size_t ws_size,
                              hipStream_t stream) {
    (void)in_sizes; (void)n_in; (void)out_size; (void)ws_size;
    const float* x      = (const float*)d_in[0];   // (4,2048,1024)
    const float* w_qkv  = (const float*)d_in[1];   // (3072,1024)
    const float* b_qkv  = (const float*)d_in[2];   // (3072,)
    const float* w_o    = (const float*)d_in[3];   // (1024,1024)
    const float* b_o    = (const float*)d_in[4];   // (1024,)
    float* out = (float*)d_out;

    char* ws = (char*)d_ws;
    u16* xb   = (u16*)(ws);                          // 16 MB  x bf16 (8192x1024)
    u16* wqb  = (u16*)(ws + 16777216);               // 6 MB   w_qkv bf16 (Q rows pre-scaled)
    u16* wob  = (u16*)(ws + 23068672);               // 2 MB   w_o bf16
    u16* qkvb = (u16*)(ws + 25165824);               // 48 MB  qkv bf16 (8192x3072)
    u16* vtb  = (u16*)(ws + 75497472);               // 16 MB  V^T bf16 (64bh x 64d x 2048s)
    u16* v2b  = (u16*)(ws + 92274688);               // 16 MB  vals2 bf16 (8192x1024)
    // scaled b_qkv lives in the vtb region: consumed by the QKV GEMM, which
    // completes (same stream) before transpose_v overwrites vtb.
    float* bsc = (float*)(ws + 75497472);

    prep_inputs<<<6156, 256, 0, stream>>>(x, w_qkv, b_qkv, w_o, xb, wqb, wob, bsc);

    // qkv = x * w_qkv^T + b_qkv   (M=8192, N=3072, K=1024), bf16 out
    gemm_abt<1><<<dim3(24, 64), 256, 0, stream>>>(xb, wqb, bsc, qkvb, 8192, 3072, 1024);

    // V^T per (b,h)
    transpose_v<<<dim3(32, 64), 256, 0, stream>>>(qkvb, vtb);

    // attention -> vals2 (bf16, quirky reshape layout)
    flash_attn<<<dim3(16, 64), 256, 0, stream>>>(qkvb, vtb, v2b);

    // out = vals2 * w_o^T + b_o   (M=8192, N=1024, K=1024), fp32 out
    gemm_abt<0><<<dim3(8, 64), 256, 0, stream>>>(v2b, wob, b_o, out, 8192, 1024, 1024);
}

// Round 4
// 274.478 us; speedup vs baseline: 1.2112x; 1.2112x over previous
//
#include <hip/hip_runtime.h>
#include <stdint.h>
#include <stddef.h>

#define DEVINL __device__ __forceinline__

typedef unsigned short u16;
typedef unsigned int u32;
typedef __attribute__((ext_vector_type(8))) short short8;
typedef __attribute__((ext_vector_type(4))) float f32x4;
typedef __attribute__((ext_vector_type(4))) u32 u32x4;
typedef __attribute__((ext_vector_type(2))) u32 u32x2;

// log2(e)/8 : folded into W_q / b_q so flash's exp2 needs no multiply
#define QSCALE 0.18033688011112042f

// ---------- helpers ----------
DEVINL u16 f2bf(float f) {
    u32 u = __builtin_bit_cast(u32, f);
    u32 r = (u + 0x7fffu + ((u >> 16) & 1u)) >> 16;   // RNE
    return (u16)r;
}

DEVINL void gld_lds16(const void* g, void* l) {
    __builtin_amdgcn_global_load_lds(
        (__attribute__((address_space(1))) u32*)(uintptr_t)g,
        (__attribute__((address_space(3))) u32*)l, 16, 0, 0);
}

// pack two fp32 -> bf16x2 by truncation (bias cancels: denominator sums the same bf16 P)
DEVINL u32 pack_bf16_trunc(float lo, float hi) {
    return __builtin_amdgcn_perm(__builtin_bit_cast(u32, hi),
                                 __builtin_bit_cast(u32, lo), 0x07060302u);
}

// ---------- fused input prep: casts + scale folding, one launch ----------
// blocks [0,4096): x -> xb ; [4096,5632): w_qkv -> wqb (Q rows scaled)
// [5632,6144): w_o -> wob ; [6144,6156): b_qkv scale -> bsc
__global__ void prep_inputs(const float* __restrict__ x, const float* __restrict__ wqkv,
                            const float* __restrict__ bqkv, const float* __restrict__ wo,
                            u16* __restrict__ xb, u16* __restrict__ wqb,
                            u16* __restrict__ wob, float* __restrict__ bsc) {
    int blk = blockIdx.x;
    if (blk < 6144) {
        const float* src; u16* dst; int base; bool qscale = false;
        if (blk < 4096)      { src = x;    dst = xb;  base = blk; }
        else if (blk < 5632) { src = wqkv; dst = wqb; base = blk - 4096; qscale = true; }
        else                 { src = wo;   dst = wob; base = blk - 5632; }
        int i = (base * 256 + threadIdx.x) * 8;
        float sc = 1.0f;
        if (qscale) { int row = i >> 10; if ((row % 192) < 64) sc = QSCALE; }
        float4 a = *(const float4*)(src + i);
        float4 c = *(const float4*)(src + i + 4);
        union { u16 s[8]; u32x4 v; } t;
        t.s[0] = f2bf(a.x * sc); t.s[1] = f2bf(a.y * sc); t.s[2] = f2bf(a.z * sc); t.s[3] = f2bf(a.w * sc);
        t.s[4] = f2bf(c.x * sc); t.s[5] = f2bf(c.y * sc); t.s[6] = f2bf(c.z * sc); t.s[7] = f2bf(c.w * sc);
        *(u32x4*)(dst + i) = t.v;
    } else {
        int i = (blk - 6144) * 256 + threadIdx.x;   // 0..3071
        float sc = ((i % 192) < 64) ? QSCALE : 1.0f;
        bsc[i] = bqkv[i] * sc;
    }
}

// ---------- QKV GEMM  qkv[M,3072] = x[M,K] * w_qkv[3072,K]^T + b ----------
// V-section columns (col%192 in [128,192)) are written TRANSPOSED straight to
// vt[bh][d][s] (one 8B store per lane); Q/K go to qkvb. 16-col groups never
// straddle section boundaries, so the branch is wave-uniform.
__global__ void gemm_qkv(const u16* __restrict__ A, const u16* __restrict__ Bm,
                         const float* __restrict__ bias, u16* __restrict__ qkvb,
                         u16* __restrict__ vtb) {
    const int K = 1024, N = 3072;
    __shared__ u16 As[128 * 32];
    __shared__ u16 Bs[128 * 32];
    const int tid = threadIdx.x;
    const int lane = tid & 63;
    const int wv = tid >> 6, wr = wv >> 1, wc = wv & 1;
    const int l15 = lane & 15, quad = lane >> 4;
    const int m0 = blockIdx.y * 128, n0 = blockIdx.x * 128;

    f32x4 acc[4][4];
#pragma unroll
    for (int i = 0; i < 4; i++)
#pragma unroll
        for (int j = 0; j < 4; j++) acc[i][j] = (f32x4){0.f, 0.f, 0.f, 0.f};

    const u16* Ab = A + (size_t)m0 * K;
    const u16* Bb = Bm + (size_t)n0 * K;
    const int srow = tid >> 2;
    const int sc8 = (tid & 3) * 8;

    for (int k0 = 0; k0 < K; k0 += 32) {
#pragma unroll
        for (int i = 0; i < 2; i++) {
            int row = i * 64 + srow;
            gld_lds16(Ab + (size_t)row * K + k0 + sc8, (char*)As + (size_t)(i * 256 + tid) * 16);
            gld_lds16(Bb + (size_t)row * K + k0 + sc8, (char*)Bs + (size_t)(i * 256 + tid) * 16);
        }
        __syncthreads();
        short8 af[4], bf8[4];
#pragma unroll
        for (int mi = 0; mi < 4; mi++)
            af[mi] = *(const short8*)(As + (wr * 64 + mi * 16 + l15) * 32 + quad * 8);
#pragma unroll
        for (int ni = 0; ni < 4; ni++)
            bf8[ni] = *(const short8*)(Bs + (wc * 64 + ni * 16 + l15) * 32 + quad * 8);
#pragma unroll
        for (int mi = 0; mi < 4; mi++)
#pragma unroll
            for (int ni = 0; ni < 4; ni++)
                acc[mi][ni] = __builtin_amdgcn_mfma_f32_16x16x32_bf16(af[mi], bf8[ni], acc[mi][ni], 0, 0, 0);
        __syncthreads();
    }

#pragma unroll
    for (int mi = 0; mi < 4; mi++) {
        int row_b = m0 + wr * 64 + mi * 16 + quad * 4;
#pragma unroll
        for (int ni = 0; ni < 4; ni++) {
            int c0 = n0 + wc * 64 + ni * 16;          // group base (16-aligned)
            int sec0 = c0 % 192;                       // section offset, wave-uniform
            float bv = bias[c0 + l15];
            float v0 = acc[mi][ni][0] + bv;
            float v1 = acc[mi][ni][1] + bv;
            float v2 = acc[mi][ni][2] + bv;
            float v3 = acc[mi][ni][3] + bv;
            if (sec0 >= 128) {
                // V element: transpose-store to vt[bh][d][s], 4 consecutive s
                int hh = c0 / 192;
                int b = row_b >> 11;
                int s = row_b & 2047;
                int d = sec0 - 128 + l15;
                u32 lo = (u32)f2bf(v0) | ((u32)f2bf(v1) << 16);
                u32 hi = (u32)f2bf(v2) | ((u32)f2bf(v3) << 16);
                *(u32x2*)(vtb + ((size_t)((b * 16 + hh) * 64 + d)) * 2048 + s) = (u32x2){lo, hi};
            } else {
                int col = c0 + l15;
                qkvb[(size_t)(row_b + 0) * N + col] = f2bf(v0);
                qkvb[(size_t)(row_b + 1) * N + col] = f2bf(v1);
                qkvb[(size_t)(row_b + 2) * N + col] = f2bf(v2);
                qkvb[(size_t)(row_b + 3) * N + col] = f2bf(v3);
            }
        }
    }
}

// ---------- out GEMM  out[M,1024] = vals2[M,K] * w_o[1024,K]^T + b_o ----------
// 128x64 tiles -> 1024 blocks (4/CU) for occupancy; fp32 output.
__global__ void gemm_out(const u16* __restrict__ A, const u16* __restrict__ Bm,
                         const float* __restrict__ bias, float* __restrict__ C) {
    const int K = 1024, N = 1024;
    __shared__ u16 As[128 * 32];   // 8 KB
    __shared__ u16 Bs[64 * 32];    // 4 KB
    const int tid = threadIdx.x;
    const int lane = tid & 63;
    const int wv = tid >> 6, wr = wv >> 1, wc = wv & 1;
    const int l15 = lane & 15, quad = lane >> 4;
    const int m0 = blockIdx.y * 128, n0 = blockIdx.x * 64;

    f32x4 acc[4][2];
#pragma unroll
    for (int i = 0; i < 4; i++)
#pragma unroll
        for (int j = 0; j < 2; j++) acc[i][j] = (f32x4){0.f, 0.f, 0.f, 0.f};

    const u16* Ab = A + (size_t)m0 * K;
    const u16* Bb = Bm + (size_t)n0 * K;
    const int srow = tid >> 2;
    const int sc8 = (tid & 3) * 8;

    for (int k0 = 0; k0 < K; k0 += 32) {
#pragma unroll
        for (int i = 0; i < 2; i++)
            gld_lds16(Ab + (size_t)(i * 64 + srow) * K + k0 + sc8, (char*)As + (size_t)(i * 256 + tid) * 16);
        gld_lds16(Bb + (size_t)srow * K + k0 + sc8, (char*)Bs + (size_t)tid * 16);
        __syncthreads();
        short8 af[4], bf8[2];
#pragma unroll
        for (int mi = 0; mi < 4; mi++)
            af[mi] = *(const short8*)(As + (wr * 64 + mi * 16 + l15) * 32 + quad * 8);
#pragma unroll
        for (int ni = 0; ni < 2; ni++)
            bf8[ni] = *(const short8*)(Bs + (wc * 32 + ni * 16 + l15) * 32 + quad * 8);
#pragma unroll
        for (int mi = 0; mi < 4; mi++)
#pragma unroll
            for (int ni = 0; ni < 2; ni++)
                acc[mi][ni] = __builtin_amdgcn_mfma_f32_16x16x32_bf16(af[mi], bf8[ni], acc[mi][ni], 0, 0, 0);
        __syncthreads();
    }

#pragma unroll
    for (int mi = 0; mi < 4; mi++) {
        int row_b = m0 + wr * 64 + mi * 16 + quad * 4;
#pragma unroll
        for (int ni = 0; ni < 2; ni++) {
            int col = n0 + wc * 32 + ni * 16 + l15;
            float bv = bias[col];
#pragma unroll
            for (int r = 0; r < 4; r++)
                C[(size_t)(row_b + r) * N + col] = acc[mi][ni][r] + bv;
        }
    }
}

// ---------- flash attention (round-2 version: all operands via LDS) ----------
// S^T = K*Q^T via MFMA (P lands key=quad*4+r, q=l15 -> b64 packed P writes),
// no online max (scale pre-folded, exp2 direct), denominator via ones-MFMA.
// 64-key tiles, Q frags in registers, LDS 36 KB -> 4 blocks/CU.
__launch_bounds__(256, 4)
__global__ void flash_attn(const u16* __restrict__ qkv, const u16* __restrict__ vt,
                           u16* __restrict__ vals2) {
    __shared__ u16 Ks[64 * 72];      // 64 keys x 64 d
    __shared__ u16 Vts[64 * 72];     // 64 d   x 64 keys
    __shared__ u16 Ps[4][32 * 72];   // per-wave 32 q x 64 keys

    const int tid = threadIdx.x;
    const int lane = tid & 63, wv = tid >> 6;
    const int l15 = lane & 15, quad = lane >> 4;
    const int s0 = blockIdx.x * 128;
    const int bh = blockIdx.y, b = bh >> 4, h = bh & 15;

    // Q fragments in registers (q rows pre-scaled by log2e/8 at cast time)
    short8 qf[2][2];
    const u16* qbase = qkv + (size_t)(b * 2048 + s0 + wv * 32) * 3072 + h * 192;
#pragma unroll
    for (int qi = 0; qi < 2; qi++)
#pragma unroll
        for (int ks = 0; ks < 2; ks++)
            qf[qi][ks] = *(const short8*)(qbase + (size_t)(qi * 16 + l15) * 3072 + ks * 32 + quad * 8);

    f32x4 o_acc[2][4];
    f32x4 sum_acc[2];
#pragma unroll
    for (int qi = 0; qi < 2; qi++) {
        sum_acc[qi] = (f32x4){0.f, 0.f, 0.f, 0.f};
#pragma unroll
        for (int nd = 0; nd < 4; nd++) o_acc[qi][nd] = (f32x4){0.f, 0.f, 0.f, 0.f};
    }

    const u16* kg = qkv + (size_t)(b * 2048) * 3072 + h * 192 + 64;
    const u16* vg = vt + (size_t)bh * 64 * 2048;
    const int srow = tid >> 2;          // 0..63
    const int sc16 = (tid & 3) * 16;    // 0,16,32,48

    const short8 ones = (short8){0x3F80, 0x3F80, 0x3F80, 0x3F80, 0x3F80, 0x3F80, 0x3F80, 0x3F80};

    for (int kb = 0; kb < 2048; kb += 64) {
        __syncthreads();
        // stage K (64 keys x 64 d) and Vt (64 d x 64 keys), 32 B per thread each
        u32x4 k0 = *(const u32x4*)(kg + (size_t)(kb + srow) * 3072 + sc16);
        u32x4 k1 = *(const u32x4*)(kg + (size_t)(kb + srow) * 3072 + sc16 + 8);
        u32x4 v0 = *(const u32x4*)(vg + (size_t)srow * 2048 + kb + sc16);
        u32x4 v1 = *(const u32x4*)(vg + (size_t)srow * 2048 + kb + sc16 + 8);
        *(u32x4*)(Ks + srow * 72 + sc16) = k0;
        *(u32x4*)(Ks + srow * 72 + sc16 + 8) = k1;
        *(u32x4*)(Vts + srow * 72 + sc16) = v0;
        *(u32x4*)(Vts + srow * 72 + sc16 + 8) = v1;
        __syncthreads();

        // S^T = K * Q^T : s_acc[ki][qi] -> key = ki*16+quad*4+r, q = qi*16+l15
        f32x4 s_acc[4][2];
#pragma unroll
        for (int ki = 0; ki < 4; ki++)
#pragma unroll
            for (int qi = 0; qi < 2; qi++) s_acc[ki][qi] = (f32x4){0.f, 0.f, 0.f, 0.f};
#pragma unroll
        for (int ki = 0; ki < 4; ki++) {
#pragma unroll
            for (int ks = 0; ks < 2; ks++) {
                short8 kf = *(const short8*)(Ks + (ki * 16 + l15) * 72 + ks * 32 + quad * 8);
#pragma unroll
                for (int qi = 0; qi < 2; qi++)
                    s_acc[ki][qi] = __builtin_amdgcn_mfma_f32_16x16x32_bf16(kf, qf[qi][ks], s_acc[ki][qi], 0, 0, 0);
            }
        }

        // P = exp2(S^T) -> truncate-pack bf16 -> per-wave LDS (A-layout rows [q][key])
#pragma unroll
        for (int ki = 0; ki < 4; ki++)
#pragma unroll
            for (int qi = 0; qi < 2; qi++) {
                float p0 = __builtin_amdgcn_exp2f(s_acc[ki][qi][0]);
                float p1 = __builtin_amdgcn_exp2f(s_acc[ki][qi][1]);
                float p2 = __builtin_amdgcn_exp2f(s_acc[ki][qi][2]);
                float p3 = __builtin_amdgcn_exp2f(s_acc[ki][qi][3]);
                u32x2 pk = (u32x2){pack_bf16_trunc(p0, p1), pack_bf16_trunc(p2, p3)};
                *(u32x2*)(Ps[wv] + (qi * 16 + l15) * 72 + ki * 16 + quad * 4) = pk;
            }

        // PV over 2 chunks of 32 keys; denominator via ones-column MFMA
#pragma unroll
        for (int c = 0; c < 2; c++) {
            short8 ap[2];
#pragma unroll
            for (int qi = 0; qi < 2; qi++)
                ap[qi] = *(const short8*)(Ps[wv] + (qi * 16 + l15) * 72 + c * 32 + quad * 8);
#pragma unroll
            for (int qi = 0; qi < 2; qi++)
                sum_acc[qi] = __builtin_amdgcn_mfma_f32_16x16x32_bf16(ap[qi], ones, sum_acc[qi], 0, 0, 0);
#pragma unroll
            for (int nd = 0; nd < 4; nd++) {
                short8 bv = *(const short8*)(Vts + (nd * 16 + l15) * 72 + c * 32 + quad * 8);
#pragma unroll
                for (int qi = 0; qi < 2; qi++)
                    o_acc[qi][nd] = __builtin_amdgcn_mfma_f32_16x16x32_bf16(ap[qi], bv, o_acc[qi][nd], 0, 0, 0);
            }
        }
    }

    // epilogue: normalize (sum is broadcast across l15 by the ones-MFMA) and
    // write vals2 in the no-head-transpose reshape layout.
#pragma unroll
    for (int qi = 0; qi < 2; qi++) {
        f32x4 inv;
#pragma unroll
        for (int r = 0; r < 4; r++) inv[r] = 1.0f / sum_acc[qi][r];
#pragma unroll
        for (int nd = 0; nd < 4; nd++) {
            int d = nd * 16 + l15;
#pragma unroll
            for (int r = 0; r < 4; r++) {
                int s = s0 + wv * 32 + qi * 16 + quad * 4 + r;
                size_t row2 = (size_t)(b * 2048 + h * 128 + (s >> 4));
                int col2 = ((s & 15) << 6) + d;
                vals2[row2 * 1024 + col2] = f2bf(o_acc[qi][nd][r] * inv[r]);
            }
        }
    }
}

// ---------- launch ----------
extern "C" void kernel_launch(void* const* d_in, const int* in_sizes, int n_in,
                              void* d_out, int out_size, void* d_ws, size_t ws_size,
                              hipStream_t stream) {
    (void)in_sizes; (void)n_in; (void)out_size; (void)ws_size;
    const float* x      = (const float*)d_in[0];   // (4,2048,1024)
    const float* w_qkv  = (const float*)d_in[1];   // (3072,1024)
    const float* b_qkv  = (const float*)d_in[2];   // (3072,)
    const float* w_o    = (const float*)d_in[3];   // (1024,1024)
    const float* b_o    = (const float*)d_in[4];   // (1024,)
    float* out = (float*)d_out;

    char* ws = (char*)d_ws;
    u16* xb   = (u16*)(ws);                          // 16 MB  x bf16 (8192x1024)
    u16* wqb  = (u16*)(ws + 16777216);               // 6 MB   w_qkv bf16 (Q rows pre-scaled)
    u16* wob  = (u16*)(ws + 23068672);               // 2 MB   w_o bf16
    u16* qkvb = (u16*)(ws + 25165824);               // 48 MB  qkv bf16 (Q,K sections only)
    u16* vtb  = (u16*)(ws + 75497472);               // 16 MB  V^T bf16 (64bh x 64d x 2048s)
    u16* v2b  = (u16*)(ws + 92274688);               // 16 MB  vals2 bf16 (8192x1024)
    // scaled b_qkv lives in the v2b region: consumed by gemm_qkv, which
    // completes (same stream) before flash_attn overwrites v2b.
    float* bsc = (float*)(ws + 92274688);

    prep_inputs<<<6156, 256, 0, stream>>>(x, w_qkv, b_qkv, w_o, xb, wqb, wob, bsc);

    // qkv = x * w_qkv^T + b_qkv ; V section written transposed to vtb
    gemm_qkv<<<dim3(24, 64), 256, 0, stream>>>(xb, wqb, bsc, qkvb, vtb);

    // attention -> vals2 (bf16, quirky reshape layout)
    flash_attn<<<dim3(16, 64), 256, 0, stream>>>(qkvb, vtb, v2b);

    // out = vals2 * w_o^T + b_o   (M=8192, N=1024, K=1024), fp32 out
    gemm_out<<<dim3(16, 64), 256, 0, stream>>>(v2b, wob, b_o, out);
}